// Round 2
// baseline (3613.444 us; speedup 1.0000x reference)
//
#include <hip/hip_runtime.h>
#include <float.h>
#include <math.h>

#define DIM 2048
#define HEADS 16
#define BATCH 2
#define SEQ 2048
#define HD 128              // head dim
#define MROWS (BATCH * SEQ) // 4096

// ---------------------------------------------------------------------------
// fp32 tiled GEMM: C(MxN) = A(MxK) @ B(KxN), all row-major, dims % 128 == 0.
// 128x128 tile, BK=16, 256 threads, 8x8 micro-tile per thread.
// ---------------------------------------------------------------------------
__global__ __launch_bounds__(256) void gemm_f32(const float* __restrict__ A,
                                                const float* __restrict__ B,
                                                float* __restrict__ C,
                                                int M, int N, int K) {
    constexpr int GM = 128, GN = 128, GK = 16;
    __shared__ float As[GK][GM + 4];   // transposed A tile, +4 pad vs bank conflicts
    __shared__ float Bs[GK][GN];

    const int t = threadIdx.x;
    const int bm = blockIdx.y * GM;
    const int bn = blockIdx.x * GN;
    const int tr = t >> 4;   // 0..15
    const int tc = t & 15;   // 0..15

    const int arow0 = t >> 2;  // A tile: float4 id -> row=id/4, c4=id%4
    const int ac4   = t & 3;
    const int brow0 = t >> 5;  // B tile: row=id/32, c4=id%32
    const int bc4   = t & 31;

    float acc[8][8] = {};

    for (int k0 = 0; k0 < K; k0 += GK) {
        // stage A tile (128x16) transposed
#pragma unroll
        for (int ii = 0; ii < 2; ++ii) {
            const int row = arow0 + ii * 64;
            const float4 a4 = *reinterpret_cast<const float4*>(
                A + (size_t)(bm + row) * K + k0 + ac4 * 4);
            As[ac4 * 4 + 0][row] = a4.x;
            As[ac4 * 4 + 1][row] = a4.y;
            As[ac4 * 4 + 2][row] = a4.z;
            As[ac4 * 4 + 3][row] = a4.w;
        }
        // stage B tile (16x128)
#pragma unroll
        for (int ii = 0; ii < 2; ++ii) {
            const int row = brow0 + ii * 8;
            *reinterpret_cast<float4*>(&Bs[row][bc4 * 4]) =
                *reinterpret_cast<const float4*>(B + (size_t)(k0 + row) * N + bn + bc4 * 4);
        }
        __syncthreads();

#pragma unroll
        for (int kk = 0; kk < GK; ++kk) {
            float a[8], b[8];
            *reinterpret_cast<float4*>(a)     = *reinterpret_cast<const float4*>(&As[kk][tr * 8]);
            *reinterpret_cast<float4*>(a + 4) = *reinterpret_cast<const float4*>(&As[kk][tr * 8 + 4]);
            *reinterpret_cast<float4*>(b)     = *reinterpret_cast<const float4*>(&Bs[kk][tc * 8]);
            *reinterpret_cast<float4*>(b + 4) = *reinterpret_cast<const float4*>(&Bs[kk][tc * 8 + 4]);
#pragma unroll
            for (int i = 0; i < 8; ++i)
#pragma unroll
                for (int jj = 0; jj < 8; ++jj)
                    acc[i][jj] = fmaf(a[i], b[jj], acc[i][jj]);
        }
        __syncthreads();
    }

#pragma unroll
    for (int i = 0; i < 8; ++i) {
        float* crow = C + (size_t)(bm + tr * 8 + i) * N + bn + tc * 8;
        *reinterpret_cast<float4*>(crow)     = make_float4(acc[i][0], acc[i][1], acc[i][2], acc[i][3]);
        *reinterpret_cast<float4*>(crow + 4) = make_float4(acc[i][4], acc[i][5], acc[i][6], acc[i][7]);
    }
}

// ---------------------------------------------------------------------------
// Flash-style attention with the reference's ANTI-causal mask (keep k > q,
// mask k <= q to -FLT_MAX). Row S-1 is fully masked -> uniform 1/S weights;
// the last q-tile processes ALL K-tiles so the online softmax reproduces
// that exactly (weights exp(0)=1 everywhere, l = S).
//
// Layout: Q/K/V/O in [b*S + s][h*HD + d] rows (i.e. (x@W) natural layout).
// Block: 256 threads = 128 q-rows; thread (rs=t>>3, j=t&7) owns rows
// {rs, rs+32, rs+64, rs+96} x d-cols [j*16, j*16+16).
// ---------------------------------------------------------------------------
constexpr int QT = 128;
constexpr int KT = 32;

__global__ __launch_bounds__(256, 2) void attn_f32(const float* __restrict__ Q,
                                                   const float* __restrict__ Kp,
                                                   const float* __restrict__ Vp,
                                                   float* __restrict__ Op) {
    __shared__ float Ks[KT][HD];       // 16 KB
    __shared__ float Vs[KT][HD];       // 16 KB
    __shared__ float P[QT][KT + 1];    // logits, padded: conflict-free bcast reads

    const int t = threadIdx.x;
    const int j = t & 7;
    const int rs = t >> 3;
    const int q0 = blockIdx.x * QT;
    const int h = blockIdx.y;
    const int b = blockIdx.z;
    const float scale = 0.08838834764831845f;  // 1/sqrt(128)

    const size_t base = ((size_t)b * SEQ) * DIM + (size_t)h * HD;
    const float* Qb = Q + base;
    const float* Kb = Kp + base;
    const float* Vb = Vp + base;
    float* Ob = Op + base;

    // Q fragments: 4 rows x own 16 cols
    float qf[4][16];
#pragma unroll
    for (int ri = 0; ri < 4; ++ri) {
        const float* src = Qb + (size_t)(q0 + rs + 32 * ri) * DIM + j * 16;
#pragma unroll
        for (int i = 0; i < 16; i += 4)
            *reinterpret_cast<float4*>(&qf[ri][i]) = *reinterpret_cast<const float4*>(src + i);
    }

    float m[4], l[4], o[4][16];
#pragma unroll
    for (int ri = 0; ri < 4; ++ri) {
        m[ri] = -INFINITY;
        l[ri] = 0.f;
#pragma unroll
        for (int i = 0; i < 16; ++i) o[ri][i] = 0.f;
    }

    // K-tiles fully below the needed region (max k in tile < q0+1) contribute
    // exactly 0 for every row here -> skip. Last q-tile: process everything
    // so the fully-masked row S-1 averages over all S positions.
    const int ktStart = (q0 == SEQ - QT) ? 0 : (q0 + 1) / KT;

    for (int kt = ktStart; kt < SEQ / KT; ++kt) {
        const int k0 = kt * KT;
        // stage K/V tile: 32x128 floats = 1024 float4 each; 4 per thread
#pragma unroll
        for (int ii = 0; ii < 4; ++ii) {
            const int id = ii * 256 + t;
            const int kr = id >> 5;
            const int c4 = id & 31;
            *reinterpret_cast<float4*>(&Ks[kr][c4 * 4]) =
                *reinterpret_cast<const float4*>(Kb + (size_t)(k0 + kr) * DIM + c4 * 4);
            *reinterpret_cast<float4*>(&Vs[kr][c4 * 4]) =
                *reinterpret_cast<const float4*>(Vb + (size_t)(k0 + kr) * DIM + c4 * 4);
        }
        __syncthreads();

        // ---- phase A: logits for this tile + per-row tile max ----
        float mt[4] = {-INFINITY, -INFINITY, -INFINITY, -INFINITY};
#pragma unroll 4
        for (int kk = 0; kk < KT; ++kk) {
            float kf[16];
#pragma unroll
            for (int i = 0; i < 16; i += 4)
                *reinterpret_cast<float4*>(&kf[i]) =
                    *reinterpret_cast<const float4*>(&Ks[kk][j * 16 + i]);
            const int kg = k0 + kk;
#pragma unroll
            for (int ri = 0; ri < 4; ++ri) {
                float s = 0.f;
#pragma unroll
                for (int i = 0; i < 16; ++i) s = fmaf(qf[ri][i], kf[i], s);
                // butterfly reduce across the 8 lanes sharing this q-row
                s += __shfl_xor(s, 1);
                s += __shfl_xor(s, 2);
                s += __shfl_xor(s, 4);
                const int qg = q0 + rs + 32 * ri;
                const float logit = (kg > qg) ? s * scale : -FLT_MAX;
                mt[ri] = fmaxf(mt[ri], logit);
                if (j == 0) P[rs + 32 * ri][kk] = logit;
            }
        }
        __syncthreads();  // P visibility across lanes (j!=0 never writes P)

        // ---- online-softmax rescale ----
#pragma unroll
        for (int ri = 0; ri < 4; ++ri) {
            const float mn = fmaxf(m[ri], mt[ri]);
            const float corr = __expf(m[ri] - mn);   // -inf path -> 0, wipes garbage
            m[ri] = mn;
            l[ri] *= corr;
#pragma unroll
            for (int i = 0; i < 16; ++i) o[ri][i] *= corr;
        }

        // ---- phase B: P*V accumulate ----
#pragma unroll 4
        for (int kk = 0; kk < KT; ++kk) {
            float vf[16];
#pragma unroll
            for (int i = 0; i < 16; i += 4)
                *reinterpret_cast<float4*>(&vf[i]) =
                    *reinterpret_cast<const float4*>(&Vs[kk][j * 16 + i]);
#pragma unroll
            for (int ri = 0; ri < 4; ++ri) {
                const float p = __expf(P[rs + 32 * ri][kk] - m[ri]);
                l[ri] += p;  // all 8 j-lanes add the same p -> consistent copies
#pragma unroll
                for (int i = 0; i < 16; ++i) o[ri][i] = fmaf(p, vf[i], o[ri][i]);
            }
        }
        __syncthreads();  // protect Ks/Vs/P before next tile's stage
    }

#pragma unroll
    for (int ri = 0; ri < 4; ++ri) {
        const float inv = 1.0f / l[ri];
        float* dst = Ob + (size_t)(q0 + rs + 32 * ri) * DIM + j * 16;
#pragma unroll
        for (int i = 0; i < 16; i += 4) {
            float4 v4;
            v4.x = o[ri][i + 0] * inv;
            v4.y = o[ri][i + 1] * inv;
            v4.z = o[ri][i + 2] * inv;
            v4.w = o[ri][i + 3] * inv;
            *reinterpret_cast<float4*>(dst + i) = v4;
        }
    }
}

// ---------------------------------------------------------------------------
// Workspace layout (floats): Q | K | V | attn_out, each 4096*2048 (32 MiB),
// total 128 MiB.
// ---------------------------------------------------------------------------
extern "C" void kernel_launch(void* const* d_in, const int* in_sizes, int n_in,
                              void* d_out, int out_size, void* d_ws, size_t ws_size,
                              hipStream_t stream) {
    const float* x  = (const float*)d_in[0];
    const float* Wq = (const float*)d_in[1];
    const float* Wk = (const float*)d_in[2];
    const float* Wv = (const float*)d_in[3];
    const float* Wo = (const float*)d_in[4];
    float* out = (float*)d_out;

    const size_t mat = (size_t)MROWS * DIM;
    float* Qw = (float*)d_ws;
    float* Kw = Qw + mat;
    float* Vw = Kw + mat;
    float* Aw = Vw + mat;

    const dim3 blk(256);
    const dim3 ggrid(DIM / 128, MROWS / 128);
    gemm_f32<<<ggrid, blk, 0, stream>>>(x, Wq, Qw, MROWS, DIM, DIM);
    gemm_f32<<<ggrid, blk, 0, stream>>>(x, Wk, Kw, MROWS, DIM, DIM);
    gemm_f32<<<ggrid, blk, 0, stream>>>(x, Wv, Vw, MROWS, DIM, DIM);

    const dim3 agrid(SEQ / QT, HEADS, BATCH);
    attn_f32<<<agrid, blk, 0, stream>>>(Qw, Kw, Vw, Aw);

    gemm_f32<<<ggrid, blk, 0, stream>>>(Aw, Wo, out, MROWS, DIM, DIM);
}